// Round 1
// baseline (1332.190 us; speedup 1.0000x reference)
//
#include <hip/hip_runtime.h>
#include <math.h>

#define EMBED   1024
#define THREEC  3072
#define NH      16
#define HD      64
#define NFEAT   64      // R * M = 2 * 32
#define RN      2
#define MM_     32
#define B_      2
#define T_      4096
#define L_      64      // our chunk length
#define NC_     64      // T_ / L_
#define BH_     32      // B_ * NH

// ---------------------------------------------------------------------------
// Generic tiled GEMM:  C[m, n] = sum_k A[m*lda + k] * W[n*K + k] + bias[n]
// 64x64 tile, BK=16, 256 threads, 4x4 micro-tile per thread. fp32.
// ---------------------------------------------------------------------------
__global__ __launch_bounds__(256) void gemm_tn(
    const float* __restrict__ A, int lda,
    const float* __restrict__ W,             // [N][K] row-major
    const float* __restrict__ bias,
    float* __restrict__ C, int ldc,
    int M, int N, int K)
{
    __shared__ float As[16][64];
    __shared__ float Ws[16][64];
    const int tid = threadIdx.x;
    const int bm = blockIdx.y * 64;
    const int bn = blockIdx.x * 64;
    const int r  = tid >> 2;            // 0..63 row within tile
    const int kq = (tid & 3) * 4;       // 0,4,8,12
    const int ty = tid >> 4;            // 0..15
    const int tx = tid & 15;            // 0..15

    float acc[4][4] = {};
    for (int k0 = 0; k0 < K; k0 += 16) {
        float4 av = *reinterpret_cast<const float4*>(&A[(size_t)(bm + r) * lda + k0 + kq]);
        float4 wv = *reinterpret_cast<const float4*>(&W[(size_t)(bn + r) * K   + k0 + kq]);
        __syncthreads();   // previous iteration's reads done
        As[kq + 0][r] = av.x; As[kq + 1][r] = av.y; As[kq + 2][r] = av.z; As[kq + 3][r] = av.w;
        Ws[kq + 0][r] = wv.x; Ws[kq + 1][r] = wv.y; Ws[kq + 2][r] = wv.z; Ws[kq + 3][r] = wv.w;
        __syncthreads();
        #pragma unroll
        for (int kk = 0; kk < 16; ++kk) {
            float4 a4 = *reinterpret_cast<const float4*>(&As[kk][ty * 4]);
            float4 w4 = *reinterpret_cast<const float4*>(&Ws[kk][tx * 4]);
            float aa[4] = {a4.x, a4.y, a4.z, a4.w};
            float ww[4] = {w4.x, w4.y, w4.z, w4.w};
            #pragma unroll
            for (int i = 0; i < 4; ++i)
                #pragma unroll
                for (int j = 0; j < 4; ++j)
                    acc[i][j] += aa[i] * ww[j];
        }
    }
    const int n = bn + tx * 4;
    #pragma unroll
    for (int i = 0; i < 4; ++i) {
        const int m = bm + ty * 4 + i;
        float4 o;
        o.x = acc[i][0] + bias[n + 0];
        o.y = acc[i][1] + bias[n + 1];
        o.z = acc[i][2] + bias[n + 2];
        o.w = acc[i][3] + bias[n + 3];
        *reinterpret_cast<float4*>(&C[(size_t)m * ldc + n]) = o;
    }
}

// ---------------------------------------------------------------------------
// Feature map for q and k.
// grid: BH_ * (T_/64) blocks, 256 threads (4 waves); each wave = one token.
// lane j (0..63): feature j = r*32 + m.
// ---------------------------------------------------------------------------
__global__ __launch_bounds__(256) void features_kernel(
    const float* __restrict__ qkv,        // [B, T, 3C]
    const float* __restrict__ omega,      // [R, H, D, M]
    const float* __restrict__ qn,         // quad_nodes [R]
    const float* __restrict__ qw,         // quad_weights [R]
    float* __restrict__ qf,               // [BH, T, 64]
    float* __restrict__ kf)               // [BH, T, 64]
{
    __shared__ float omg[RN * HD * MM_];  // 4096 floats: [r][d][m]
    const int tid  = threadIdx.x;
    const int bh   = blockIdx.x & 31;
    const int tb   = blockIdx.x >> 5;     // 0..63, 64 tokens each
    const int b    = bh >> 4, h = bh & 15;

    for (int i = tid; i < RN * HD * MM_; i += 256) {
        const int rr   = i >> 11;         // / 2048
        const int rest = i & 2047;        // d*32 + m
        omg[i] = omega[(size_t)(rr * NH + h) * 2048 + rest];
    }
    __syncthreads();

    const int wave = tid >> 6;
    const int lane = tid & 63;
    const int rr = lane >> 5;
    const int mmi = lane & 31;
    const float s_r   = qn[rr];
    const float sq2s  = sqrtf(2.0f * fmaxf(s_r, 0.0f));
    const float scale = sqrtf(fmaxf(qw[rr], 0.0f)) * (1.0f / 32.0f); // sqw * inv_sqrt_m^2

    for (int tt = 0; tt < 16; ++tt) {
        const int t = tb * 64 + tt * 4 + wave;
        const size_t base = ((size_t)(b * T_ + t)) * THREEC + h * HD;
        #pragma unroll
        for (int p = 0; p < 2; ++p) {
            const float z = qkv[base + p * EMBED + lane];
            float ss = z * z;
            #pragma unroll
            for (int off = 32; off; off >>= 1) ss += __shfl_xor(ss, off, 64);
            const float inv = 1.0f / fmaxf(sqrtf(ss), 1e-12f);
            const float zn = z * inv;
            float proj = 0.0f;
            #pragma unroll
            for (int d = 0; d < 64; ++d) {
                const float znd = __shfl(zn, d, 64);
                proj += znd * omg[rr * 2048 + d * 32 + mmi];
            }
            const float arg = fminf(fmaxf(proj * sq2s - s_r, -20.0f), 20.0f);
            const float val = proj * proj * expf(arg) * scale;
            float* dst = (p == 0) ? qf : kf;
            dst[((size_t)bh * T_ + t) * NFEAT + lane] = val;
        }
    }
}

// ---------------------------------------------------------------------------
// Per-chunk KV sums:  S[f,d] = sum_t kf[t,f]*v[t,d],  s[f] = sum_t kf[t,f]
// grid: BH_*NC_ blocks (chunk = bh*NC_ + c), 256 threads.
// ---------------------------------------------------------------------------
__global__ __launch_bounds__(256) void chunk_sums(
    const float* __restrict__ kf,
    const float* __restrict__ qkv,        // for v
    float* __restrict__ cKV,              // [BH*NC, 64, 64]
    float* __restrict__ cK)               // [BH*NC, 64]
{
    __shared__ float kfs[L_][NFEAT];
    __shared__ float vs[L_][HD];
    const int tid = threadIdx.x;
    const int chunk = blockIdx.x;
    const int bh = chunk / NC_, c = chunk % NC_;
    const int b = bh >> 4, h = bh & 15;
    const int t0 = c * L_;

    for (int i = tid; i < L_ * NFEAT; i += 256) {
        const int t = i >> 6, f = i & 63;
        kfs[t][f] = kf[((size_t)bh * T_ + t0 + t) * NFEAT + f];
        vs[t][f]  = qkv[((size_t)(b * T_ + t0 + t)) * THREEC + 2 * EMBED + h * HD + f];
    }
    __syncthreads();

    const int f  = tid >> 2;
    const int d0 = (tid & 3) * 16;
    float acc[16] = {};
    float ks = 0.0f;
    for (int t = 0; t < L_; ++t) {
        const float kft = kfs[t][f];
        ks += kft;
        #pragma unroll
        for (int j = 0; j < 16; ++j) acc[j] += kft * vs[t][d0 + j];
    }
    float* dst = cKV + (size_t)chunk * NFEAT * HD + f * HD + d0;
    #pragma unroll
    for (int j = 0; j < 16; ++j) dst[j] = acc[j];
    if ((tid & 3) == 0) cK[(size_t)chunk * NFEAT + f] = ks;
}

// ---------------------------------------------------------------------------
// Exclusive prefix over chunks within each (b,h). grid: BH_ blocks, 256 thr.
// Replaces cKV[c] with sum of chunks 0..c-1 (same for cK).
// ---------------------------------------------------------------------------
__global__ __launch_bounds__(256) void prefix_scan(
    float* __restrict__ cKV, float* __restrict__ cK)
{
    const int bh = blockIdx.x;
    const int tid = threadIdx.x;
    float pref[16];
    #pragma unroll
    for (int j = 0; j < 16; ++j) pref[j] = 0.0f;
    float prefk = 0.0f;
    for (int c = 0; c < NC_; ++c) {
        float* base = cKV + ((size_t)bh * NC_ + c) * (NFEAT * HD) + tid * 16;
        float4* b4 = reinterpret_cast<float4*>(base);
        float tmp[16];
        #pragma unroll
        for (int q = 0; q < 4; ++q) {
            float4 v = b4[q];
            tmp[q * 4 + 0] = v.x; tmp[q * 4 + 1] = v.y;
            tmp[q * 4 + 2] = v.z; tmp[q * 4 + 3] = v.w;
        }
        #pragma unroll
        for (int q = 0; q < 4; ++q) {
            float4 v;
            v.x = pref[q * 4 + 0]; v.y = pref[q * 4 + 1];
            v.z = pref[q * 4 + 2]; v.w = pref[q * 4 + 3];
            b4[q] = v;
        }
        #pragma unroll
        for (int j = 0; j < 16; ++j) pref[j] += tmp[j];
        if (tid < 64) {
            float* kb = cK + ((size_t)bh * NC_ + c) * NFEAT + tid;
            const float tk = *kb;
            *kb = prefk;
            prefk += tk;
        }
    }
}

// ---------------------------------------------------------------------------
// Intra-chunk causal attention + inter-chunk state.
// out[t,d] = ( sum_{s<=t} A[t,s] V[s,d] + sum_f Qf[t,f] KVp[f,d] ) / den
// den[t]   = max( rowsum(A[t,:]) + Qf[t]·kp , 1e-6 )
// Output written into the q-region of qkv -> [B,T,C] layout for final GEMM.
// ---------------------------------------------------------------------------
__global__ __launch_bounds__(256) void intra_attn(
    const float* __restrict__ qf,
    const float* __restrict__ kf,
    const float* qkv_v,                   // aliases qkv (v region read)
    const float* __restrict__ cKV,
    const float* __restrict__ cK,
    float* qkv_out)                       // aliases qkv (q region write)
{
    __shared__ float Qs[L_][NFEAT];
    __shared__ float Ks[L_][NFEAT];       // phase 2: reused for KVprefix
    __shared__ float Vs[L_][HD];
    __shared__ float At[L_][L_];          // A transposed: At[s][t]
    const int tid = threadIdx.x;
    const int chunk = blockIdx.x;
    const int bh = chunk / NC_, c = chunk % NC_;
    const int b = bh >> 4, h = bh & 15;
    const int t0 = c * L_;

    for (int i = tid; i < L_ * NFEAT; i += 256) {
        const int t = i >> 6, f = i & 63;
        Qs[t][f] = qf[((size_t)bh * T_ + t0 + t) * NFEAT + f];
        Ks[t][f] = kf[((size_t)bh * T_ + t0 + t) * NFEAT + f];
        Vs[t][f] = qkv_v[((size_t)(b * T_ + t0 + t)) * THREEC + 2 * EMBED + h * HD + f];
    }
    __syncthreads();

    const int t = tid >> 2;
    const int g = tid & 3;

    // phase 1: A[t][s] for s in [g*16, g*16+16), causal mask s <= t
    float rowsum = 0.0f;
    const float4* qrow = reinterpret_cast<const float4*>(&Qs[t][0]);
    for (int si = 0; si < 16; ++si) {
        const int s = g * 16 + si;
        float a = 0.0f;
        if (s <= t) {
            const float4* krow = reinterpret_cast<const float4*>(&Ks[s][0]);
            #pragma unroll
            for (int f4 = 0; f4 < 16; ++f4) {
                const float4 qa = qrow[f4];
                const float4 kb = krow[f4];
                a += qa.x * kb.x + qa.y * kb.y + qa.z * kb.z + qa.w * kb.w;
            }
        }
        At[s][t] = a;
        rowsum += a;
    }
    rowsum += __shfl_xor(rowsum, 1, 64);
    rowsum += __shfl_xor(rowsum, 2, 64);
    __syncthreads();

    // phase 2: load KV prefix into Ks
    for (int i = tid; i < NFEAT * HD; i += 256) {
        reinterpret_cast<float*>(Ks)[i] = cKV[(size_t)chunk * (NFEAT * HD) + i];
    }
    __syncthreads();

    // phase 3: ctx and den
    const int d0 = g * 16;
    float acc[16] = {};
    for (int s = 0; s < L_; ++s) {
        const float a = At[s][t];
        #pragma unroll
        for (int j = 0; j < 16; ++j) acc[j] += a * Vs[s][d0 + j];
    }
    float qkp = 0.0f;
    const float* kp = cK + (size_t)chunk * NFEAT;
    for (int f = 0; f < 64; ++f) {
        const float qtf = Qs[t][f];
        qkp += qtf * kp[f];
        #pragma unroll
        for (int j = 0; j < 16; ++j) acc[j] += qtf * Ks[f][d0 + j];
    }
    const float den = fmaxf(rowsum + qkp, 1e-6f);
    const float invden = 1.0f / den;
    float* dst = qkv_out + ((size_t)(b * T_ + t0 + t)) * THREEC + h * HD + d0;
    #pragma unroll
    for (int j = 0; j < 16; ++j) dst[j] = acc[j] * invden;
}

// ---------------------------------------------------------------------------
extern "C" void kernel_launch(void* const* d_in, const int* in_sizes, int n_in,
                              void* d_out, int out_size, void* d_ws, size_t ws_size,
                              hipStream_t stream)
{
    const float* x     = (const float*)d_in[0];   // [B,T,C]
    const float* w_qkv = (const float*)d_in[1];   // [3C,C]
    const float* b_qkv = (const float*)d_in[2];   // [3C]
    const float* w_out = (const float*)d_in[3];   // [C,C]
    const float* b_out = (const float*)d_in[4];   // [C]
    const float* omega = (const float*)d_in[5];   // [R,H,D,M]
    const float* qn    = (const float*)d_in[6];   // [R]
    const float* qw    = (const float*)d_in[7];   // [R]
    float* out = (float*)d_out;

    // workspace layout (floats)
    float* ws   = (float*)d_ws;
    float* qkv  = ws;                                  // 25,165,824
    float* qf   = qkv + (size_t)B_ * T_ * THREEC;      //  8,388,608
    float* kf   = qf  + (size_t)BH_ * T_ * NFEAT;      //  8,388,608
    float* cKV  = kf  + (size_t)BH_ * T_ * NFEAT;      //  8,388,608
    float* cK   = cKV + (size_t)BH_ * NC_ * NFEAT * HD;//    131,072

    const int M = B_ * T_;   // 8192

    // 1. qkv = x @ w_qkv^T + b_qkv
    {
        dim3 grid(THREEC / 64, M / 64);
        gemm_tn<<<grid, 256, 0, stream>>>(x, EMBED, w_qkv, b_qkv, qkv, THREEC,
                                          M, THREEC, EMBED);
    }
    // 2. features for q and k
    {
        dim3 grid(BH_ * (T_ / 64));
        features_kernel<<<grid, 256, 0, stream>>>(qkv, omega, qn, qw, qf, kf);
    }
    // 3. per-chunk KV sums
    chunk_sums<<<dim3(BH_ * NC_), 256, 0, stream>>>(kf, qkv, cKV, cK);
    // 4. exclusive prefix over chunks
    prefix_scan<<<dim3(BH_), 256, 0, stream>>>(cKV, cK);
    // 5. intra-chunk attention (writes into q region of qkv)
    intra_attn<<<dim3(BH_ * NC_), 256, 0, stream>>>(qf, kf, qkv, cKV, cK, qkv);
    // 6. out = attn @ w_out^T + b_out   (attn read from q region, lda=3072)
    {
        dim3 grid(EMBED / 64, M / 64);
        gemm_tn<<<grid, 256, 0, stream>>>(qkv, THREEC, w_out, b_out, out, EMBED,
                                          M, EMBED, EMBED);
    }
}

// Round 2
// 548.285 us; speedup vs baseline: 2.4297x; 2.4297x over previous
//
#include <hip/hip_runtime.h>
#include <math.h>

#define EMBED   1024
#define THREEC  3072
#define NH      16
#define HD      64
#define NFEAT   64      // R * M = 2 * 32
#define RN      2
#define MM_     32
#define B_      2
#define T_      4096
#define L_      64      // chunk length
#define NC_     64      // T_ / L_
#define BH_     32      // B_ * NH

typedef __attribute__((ext_vector_type(8))) short bf16x8;
typedef __attribute__((ext_vector_type(4))) float f32x4;

__device__ __forceinline__ float bf2f(short s) {
    unsigned u = ((unsigned)(unsigned short)s) << 16;
    return __builtin_bit_cast(float, u);
}
__device__ __forceinline__ short f2bf(float f) {
    unsigned u = __builtin_bit_cast(unsigned, f);
    u += 0x7fff + ((u >> 16) & 1);
    return (short)(u >> 16);
}
__device__ __forceinline__ void gload16(const short* g, short* l) {
    __builtin_amdgcn_global_load_lds(
        (const __attribute__((address_space(1))) void*)g,
        (__attribute__((address_space(3))) void*)l, 16, 0, 0);
}

// ---------------------------------------------------------------------------
// f32 -> bf16 cast, 8 elems/thread
// ---------------------------------------------------------------------------
__global__ __launch_bounds__(256) void cast_kernel(
    const float* __restrict__ in, short* __restrict__ out, int n8)
{
    int i = blockIdx.x * 256 + threadIdx.x;
    if (i >= n8) return;
    const float4* p = (const float4*)in + (size_t)i * 2;
    float4 a = p[0], b = p[1];
    bf16x8 o = { f2bf(a.x), f2bf(a.y), f2bf(a.z), f2bf(a.w),
                 f2bf(b.x), f2bf(b.y), f2bf(b.z), f2bf(b.w) };
    *((bf16x8*)out + i) = o;
}

// ---------------------------------------------------------------------------
// bf16 MFMA GEMM, m97 structure: 128x128 tile, BK=32, 256 thr (4 waves,
// each 64x64), global_load_lds w16, double-buffered LDS.
// C[m,n] = sum_k A[m*K+k] * W[n*K+k] + bias[n]
// OUTBF: 1 -> bf16 C, 0 -> fp32 C.
// ---------------------------------------------------------------------------
template<int OUTBF>
__global__ __launch_bounds__(256) void gemm_bf16(
    const short* __restrict__ A,      // [M][K] bf16
    const short* __restrict__ W,      // [N][K] bf16
    const float* __restrict__ bias,   // [N]
    float* __restrict__ Cf, short* __restrict__ Cb,
    int M, int N, int K)
{
    __shared__ short lA[2][128 * 32];
    __shared__ short lB[2][128 * 32];
    const int tid  = threadIdx.x;
    const int bm   = blockIdx.y * 128;
    const int bn   = blockIdx.x * 128;
    const int lane = tid & 63;
    const int wave = tid >> 6;
    const int row0 = (wave >> 1) * 64;
    const int col0 = (wave & 1) * 64;
    const int lr   = lane & 15;
    const int kg8  = (lane >> 4) * 8;

    f32x4 acc[4][4] = {};

#define STAGE(buf, k0)                                                        \
    {                                                                         \
        _Pragma("unroll")                                                     \
        for (int i = 0; i < 2; ++i) {                                         \
            int idx = i * 256 + tid;                                          \
            int row = idx >> 2, kq = (idx & 3) * 8;                           \
            gload16(&A[(size_t)(bm + row) * K + (k0) + kq], &lA[buf][idx * 8]); \
            gload16(&W[(size_t)(bn + row) * K + (k0) + kq], &lB[buf][idx * 8]); \
        }                                                                     \
    }

    const int KT = K >> 5;
    STAGE(0, 0);
    __syncthreads();
    int cur = 0;
    for (int kt = 0; kt < KT; ++kt) {
        if (kt + 1 < KT) STAGE(cur ^ 1, (kt + 1) * 32);
        const short* As = lA[cur];
        const short* Bs = lB[cur];
        bf16x8 af[4], bfr[4];
        #pragma unroll
        for (int m = 0; m < 4; ++m)
            af[m] = *(const bf16x8*)&As[(row0 + m * 16 + lr) * 32 + kg8];
        #pragma unroll
        for (int n = 0; n < 4; ++n)
            bfr[n] = *(const bf16x8*)&Bs[(col0 + n * 16 + lr) * 32 + kg8];
        #pragma unroll
        for (int m = 0; m < 4; ++m)
            #pragma unroll
            for (int n = 0; n < 4; ++n)
                acc[m][n] = __builtin_amdgcn_mfma_f32_16x16x32_bf16(
                    af[m], bfr[n], acc[m][n], 0, 0, 0);
        __syncthreads();
        cur ^= 1;
    }
#undef STAGE

    // C/D layout: col = lane&15, row = (lane>>4)*4 + j
    #pragma unroll
    for (int n = 0; n < 4; ++n) {
        const int col = bn + col0 + n * 16 + (lane & 15);
        const float bv = bias[col];
        #pragma unroll
        for (int m = 0; m < 4; ++m) {
            const int rbase = bm + row0 + m * 16 + (lane >> 4) * 4;
            #pragma unroll
            for (int j = 0; j < 4; ++j) {
                const float v = acc[m][n][j] + bv;
                if (OUTBF) Cb[(size_t)(rbase + j) * N + col] = f2bf(v);
                else       Cf[(size_t)(rbase + j) * N + col] = v;
            }
        }
    }
}

// ---------------------------------------------------------------------------
// Feature map for q and k (reads bf16 qkv).
// grid: BH_ * (T_/64) blocks, 256 threads (4 waves); each wave = one token.
// ---------------------------------------------------------------------------
__global__ __launch_bounds__(256) void features_kernel(
    const short* __restrict__ qkvb,       // [B, T, 3C] bf16
    const float* __restrict__ omega,      // [R, H, D, M]
    const float* __restrict__ qn,
    const float* __restrict__ qw,
    float* __restrict__ qf,               // [BH, T, 64]
    float* __restrict__ kf)
{
    __shared__ float omg[RN * HD * MM_];
    const int tid  = threadIdx.x;
    const int bh   = blockIdx.x & 31;
    const int tb   = blockIdx.x >> 5;
    const int b    = bh >> 4, h = bh & 15;

    for (int i = tid; i < RN * HD * MM_; i += 256) {
        const int rr   = i >> 11;
        const int rest = i & 2047;
        omg[i] = omega[(size_t)(rr * NH + h) * 2048 + rest];
    }
    __syncthreads();

    const int wave = tid >> 6;
    const int lane = tid & 63;
    const int rr = lane >> 5;
    const int mmi = lane & 31;
    const float s_r   = qn[rr];
    const float sq2s  = sqrtf(2.0f * fmaxf(s_r, 0.0f));
    const float scale = sqrtf(fmaxf(qw[rr], 0.0f)) * (1.0f / 32.0f);

    for (int tt = 0; tt < 16; ++tt) {
        const int t = tb * 64 + tt * 4 + wave;
        const size_t base = ((size_t)(b * T_ + t)) * THREEC + h * HD;
        #pragma unroll
        for (int p = 0; p < 2; ++p) {
            const float z = bf2f(qkvb[base + p * EMBED + lane]);
            float ss = z * z;
            #pragma unroll
            for (int off = 32; off; off >>= 1) ss += __shfl_xor(ss, off, 64);
            const float inv = 1.0f / fmaxf(sqrtf(ss), 1e-12f);
            const float zn = z * inv;
            float proj = 0.0f;
            #pragma unroll
            for (int d = 0; d < 64; ++d) {
                const float znd = __shfl(zn, d, 64);
                proj += znd * omg[rr * 2048 + d * 32 + mmi];
            }
            const float arg = fminf(fmaxf(proj * sq2s - s_r, -20.0f), 20.0f);
            const float val = proj * proj * expf(arg) * scale;
            float* dst = (p == 0) ? qf : kf;
            dst[((size_t)bh * T_ + t) * NFEAT + lane] = val;
        }
    }
}

// ---------------------------------------------------------------------------
// Per-chunk KV sums
// ---------------------------------------------------------------------------
__global__ __launch_bounds__(256) void chunk_sums(
    const float* __restrict__ kf,
    const short* __restrict__ qkvb,
    float* __restrict__ cKV,              // [BH*NC, 64, 64]
    float* __restrict__ cK)               // [BH*NC, 64]
{
    __shared__ float kfs[L_][NFEAT];
    __shared__ float vs[L_][HD];
    const int tid = threadIdx.x;
    const int chunk = blockIdx.x;
    const int bh = chunk / NC_, c = chunk % NC_;
    const int b = bh >> 4, h = bh & 15;
    const int t0 = c * L_;

    for (int i = tid; i < L_ * NFEAT; i += 256) {
        const int t = i >> 6, f = i & 63;
        kfs[t][f] = kf[((size_t)bh * T_ + t0 + t) * NFEAT + f];
        vs[t][f]  = bf2f(qkvb[((size_t)(b * T_ + t0 + t)) * THREEC + 2 * EMBED + h * HD + f]);
    }
    __syncthreads();

    const int f  = tid >> 2;
    const int d0 = (tid & 3) * 16;
    float acc[16] = {};
    float ks = 0.0f;
    for (int t = 0; t < L_; ++t) {
        const float kft = kfs[t][f];
        ks += kft;
        #pragma unroll
        for (int j = 0; j < 16; ++j) acc[j] += kft * vs[t][d0 + j];
    }
    float* dst = cKV + (size_t)chunk * NFEAT * HD + f * HD + d0;
    #pragma unroll
    for (int j = 0; j < 16; ++j) dst[j] = acc[j];
    if ((tid & 3) == 0) cK[(size_t)chunk * NFEAT + f] = ks;
}

// ---------------------------------------------------------------------------
// Exclusive prefix over chunks
// ---------------------------------------------------------------------------
__global__ __launch_bounds__(256) void prefix_scan(
    float* __restrict__ cKV, float* __restrict__ cK)
{
    const int bh = blockIdx.x;
    const int tid = threadIdx.x;
    float pref[16];
    #pragma unroll
    for (int j = 0; j < 16; ++j) pref[j] = 0.0f;
    float prefk = 0.0f;
    for (int c = 0; c < NC_; ++c) {
        float* base = cKV + ((size_t)bh * NC_ + c) * (NFEAT * HD) + tid * 16;
        float4* b4 = reinterpret_cast<float4*>(base);
        float tmp[16];
        #pragma unroll
        for (int q = 0; q < 4; ++q) {
            float4 v = b4[q];
            tmp[q * 4 + 0] = v.x; tmp[q * 4 + 1] = v.y;
            tmp[q * 4 + 2] = v.z; tmp[q * 4 + 3] = v.w;
        }
        #pragma unroll
        for (int q = 0; q < 4; ++q) {
            float4 v;
            v.x = pref[q * 4 + 0]; v.y = pref[q * 4 + 1];
            v.z = pref[q * 4 + 2]; v.w = pref[q * 4 + 3];
            b4[q] = v;
        }
        #pragma unroll
        for (int j = 0; j < 16; ++j) pref[j] += tmp[j];
        if (tid < 64) {
            float* kb = cK + ((size_t)bh * NC_ + c) * NFEAT + tid;
            const float tk = *kb;
            *kb = prefk;
            prefk += tk;
        }
    }
}

// ---------------------------------------------------------------------------
// Intra-chunk causal attention; writes bf16 attn output [B*T, C]
// ---------------------------------------------------------------------------
__global__ __launch_bounds__(256) void intra_attn(
    const float* __restrict__ qf,
    const float* __restrict__ kf,
    const short* __restrict__ qkvb,       // v region read (bf16)
    const float* __restrict__ cKV,
    const float* __restrict__ cK,
    short* __restrict__ attnb)            // [B*T, EMBED] bf16
{
    __shared__ float Qs[L_][NFEAT];
    __shared__ float Ks[L_][NFEAT];       // phase 2: reused for KVprefix
    __shared__ float Vs[L_][HD];
    __shared__ float At[L_][L_];
    const int tid = threadIdx.x;
    const int chunk = blockIdx.x;
    const int bh = chunk / NC_, c = chunk % NC_;
    const int b = bh >> 4, h = bh & 15;
    const int t0 = c * L_;

    for (int i = tid; i < L_ * NFEAT; i += 256) {
        const int t = i >> 6, f = i & 63;
        Qs[t][f] = qf[((size_t)bh * T_ + t0 + t) * NFEAT + f];
        Ks[t][f] = kf[((size_t)bh * T_ + t0 + t) * NFEAT + f];
        Vs[t][f] = bf2f(qkvb[((size_t)(b * T_ + t0 + t)) * THREEC + 2 * EMBED + h * HD + f]);
    }
    __syncthreads();

    const int t = tid >> 2;
    const int g = tid & 3;

    float rowsum = 0.0f;
    const float4* qrow = reinterpret_cast<const float4*>(&Qs[t][0]);
    for (int si = 0; si < 16; ++si) {
        const int s = g * 16 + si;
        float a = 0.0f;
        if (s <= t) {
            const float4* krow = reinterpret_cast<const float4*>(&Ks[s][0]);
            #pragma unroll
            for (int f4 = 0; f4 < 16; ++f4) {
                const float4 qa = qrow[f4];
                const float4 kb = krow[f4];
                a += qa.x * kb.x + qa.y * kb.y + qa.z * kb.z + qa.w * kb.w;
            }
        }
        At[s][t] = a;
        rowsum += a;
    }
    rowsum += __shfl_xor(rowsum, 1, 64);
    rowsum += __shfl_xor(rowsum, 2, 64);
    __syncthreads();

    for (int i = tid; i < NFEAT * HD; i += 256) {
        reinterpret_cast<float*>(Ks)[i] = cKV[(size_t)chunk * (NFEAT * HD) + i];
    }
    __syncthreads();

    const int d0 = g * 16;
    float acc[16] = {};
    for (int s = 0; s < L_; ++s) {
        const float a = At[s][t];
        #pragma unroll
        for (int j = 0; j < 16; ++j) acc[j] += a * Vs[s][d0 + j];
    }
    float qkp = 0.0f;
    const float* kp = cK + (size_t)chunk * NFEAT;
    for (int f = 0; f < 64; ++f) {
        const float qtf = Qs[t][f];
        qkp += qtf * kp[f];
        #pragma unroll
        for (int j = 0; j < 16; ++j) acc[j] += qtf * Ks[f][d0 + j];
    }
    const float den = fmaxf(rowsum + qkp, 1e-6f);
    const float invden = 1.0f / den;

    bf16x8 o0, o1;
    #pragma unroll
    for (int j = 0; j < 8; ++j) {
        o0[j] = f2bf(acc[j] * invden);
        o1[j] = f2bf(acc[8 + j] * invden);
    }
    bf16x8* dst = (bf16x8*)(attnb + ((size_t)(b * T_ + t0 + t)) * EMBED + h * HD + d0);
    dst[0] = o0;
    dst[1] = o1;
}

// ---------------------------------------------------------------------------
extern "C" void kernel_launch(void* const* d_in, const int* in_sizes, int n_in,
                              void* d_out, int out_size, void* d_ws, size_t ws_size,
                              hipStream_t stream)
{
    const float* x     = (const float*)d_in[0];
    const float* w_qkv = (const float*)d_in[1];
    const float* b_qkv = (const float*)d_in[2];
    const float* w_out = (const float*)d_in[3];
    const float* b_out = (const float*)d_in[4];
    const float* omega = (const float*)d_in[5];
    const float* qn    = (const float*)d_in[6];
    const float* qw    = (const float*)d_in[7];
    float* out = (float*)d_out;

    // workspace layout
    short* xb    = (short*)d_ws;               //  8,388,608
    short* wqb   = xb    + 8388608;            //  3,145,728
    short* wob   = wqb   + 3145728;            //  1,048,576
    short* qkvb  = wob   + 1048576;            // 25,165,824
    short* attnb = qkvb  + 25165824;           //  8,388,608
    float* qf    = (float*)(attnb + 8388608);  //  8,388,608
    float* kf    = qf  + 8388608;
    float* cKV   = kf  + 8388608;              //  8,388,608
    float* cK    = cKV + 8388608;              //    131,072

    const int M = B_ * T_;   // 8192

    // casts
    cast_kernel<<<dim3(8388608 / 8 / 256), 256, 0, stream>>>(x, xb, 8388608 / 8);
    cast_kernel<<<dim3(3145728 / 8 / 256), 256, 0, stream>>>(w_qkv, wqb, 3145728 / 8);
    cast_kernel<<<dim3(1048576 / 8 / 256), 256, 0, stream>>>(w_out, wob, 1048576 / 8);

    // 1. qkv = x @ w_qkv^T + b_qkv  (bf16 out)
    gemm_bf16<1><<<dim3(THREEC / 128, M / 128), 256, 0, stream>>>(
        xb, wqb, b_qkv, nullptr, qkvb, M, THREEC, EMBED);
    // 2. features
    features_kernel<<<dim3(BH_ * (T_ / 64)), 256, 0, stream>>>(qkvb, omega, qn, qw, qf, kf);
    // 3. per-chunk KV sums
    chunk_sums<<<dim3(BH_ * NC_), 256, 0, stream>>>(kf, qkvb, cKV, cK);
    // 4. exclusive prefix over chunks
    prefix_scan<<<dim3(BH_), 256, 0, stream>>>(cKV, cK);
    // 5. intra-chunk attention -> bf16 attn [B*T, C]
    intra_attn<<<dim3(BH_ * NC_), 256, 0, stream>>>(qf, kf, qkvb, cKV, cK, attnb);
    // 6. out = attn @ w_out^T + b_out (fp32 out)
    gemm_bf16<0><<<dim3(EMBED / 128, M / 128), 256, 0, stream>>>(
        attnb, wob, b_out, out, nullptr, M, EMBED, EMBED);
}

// Round 3
// 369.978 us; speedup vs baseline: 3.6007x; 1.4819x over previous
//
#include <hip/hip_runtime.h>
#include <math.h>

#define EMBED   1024
#define THREEC  3072
#define NH      16
#define HD      64
#define NFEAT   64      // R * M = 2 * 32
#define RN      2
#define MM_     32
#define B_      2
#define T_      4096
#define L_      64      // chunk length
#define NC_     64      // T_ / L_
#define BH_     32      // B_ * NH

typedef __attribute__((ext_vector_type(8))) short bf16x8;
typedef __attribute__((ext_vector_type(4))) float f32x4;

__device__ __forceinline__ float bf2f(short s) {
    unsigned u = ((unsigned)(unsigned short)s) << 16;
    return __builtin_bit_cast(float, u);
}
__device__ __forceinline__ short f2bf(float f) {
    unsigned u = __builtin_bit_cast(unsigned, f);
    u += 0x7fff + ((u >> 16) & 1);
    return (short)(u >> 16);
}
__device__ __forceinline__ void gload16(const short* g, short* l) {
    __builtin_amdgcn_global_load_lds(
        (const __attribute__((address_space(1))) void*)g,
        (__attribute__((address_space(3))) void*)l, 16, 0, 0);
}

// ---------------------------------------------------------------------------
// f32 -> bf16 cast, 8 elems/thread
// ---------------------------------------------------------------------------
__global__ __launch_bounds__(256) void cast_kernel(
    const float* __restrict__ in, short* __restrict__ out, int n8)
{
    int i = blockIdx.x * 256 + threadIdx.x;
    if (i >= n8) return;
    const float4* p = (const float4*)in + (size_t)i * 2;
    float4 a = p[0], b = p[1];
    bf16x8 o = { f2bf(a.x), f2bf(a.y), f2bf(a.z), f2bf(a.w),
                 f2bf(b.x), f2bf(b.y), f2bf(b.z), f2bf(b.w) };
    *((bf16x8*)out + i) = o;
}

// ---------------------------------------------------------------------------
// omega [R,H,D,M] fp32 -> omgT[h][f=r*32+m][d] bf16 hi/lo split
// ---------------------------------------------------------------------------
__global__ __launch_bounds__(256) void omega_prep(
    const float* __restrict__ omega, short* __restrict__ hi, short* __restrict__ lo)
{
    int i = blockIdx.x * 256 + threadIdx.x;   // over H*F*D = 65536
    if (i >= NH * NFEAT * HD) return;
    int d = i & 63;
    int f = (i >> 6) & 63;
    int h = i >> 12;
    int r = f >> 5, m = f & 31;
    float w = omega[(((size_t)(r * NH + h) * HD + d) * MM_) + m];
    short a = f2bf(w);
    hi[i] = a;
    lo[i] = f2bf(w - bf2f(a));
}

// ---------------------------------------------------------------------------
// bf16 MFMA GEMM, m97 structure: 128x128 tile, BK=32, 256 thr (4 waves,
// each 64x64), global_load_lds w16, double-buffered LDS.
// C[m,n] = sum_k A[m*K+k] * W[n*K+k] + bias[n]
// OUTBF: 1 -> bf16 C, 0 -> fp32 C.
// ---------------------------------------------------------------------------
template<int OUTBF>
__global__ __launch_bounds__(256) void gemm_bf16(
    const short* __restrict__ A,      // [M][K] bf16
    const short* __restrict__ W,      // [N][K] bf16
    const float* __restrict__ bias,   // [N]
    float* __restrict__ Cf, short* __restrict__ Cb,
    int M, int N, int K)
{
    __shared__ short lA[2][128 * 32];
    __shared__ short lB[2][128 * 32];
    const int tid  = threadIdx.x;
    const int bm   = blockIdx.y * 128;
    const int bn   = blockIdx.x * 128;
    const int lane = tid & 63;
    const int wave = tid >> 6;
    const int row0 = (wave >> 1) * 64;
    const int col0 = (wave & 1) * 64;
    const int lr   = lane & 15;
    const int kg8  = (lane >> 4) * 8;

    f32x4 acc[4][4] = {};

#define STAGE(buf, k0)                                                        \
    {                                                                         \
        _Pragma("unroll")                                                     \
        for (int i = 0; i < 2; ++i) {                                         \
            int idx = i * 256 + tid;                                          \
            int row = idx >> 2, kq = (idx & 3) * 8;                           \
            gload16(&A[(size_t)(bm + row) * K + (k0) + kq], &lA[buf][idx * 8]); \
            gload16(&W[(size_t)(bn + row) * K + (k0) + kq], &lB[buf][idx * 8]); \
        }                                                                     \
    }

    const int KT = K >> 5;
    STAGE(0, 0);
    __syncthreads();
    int cur = 0;
    for (int kt = 0; kt < KT; ++kt) {
        if (kt + 1 < KT) STAGE(cur ^ 1, (kt + 1) * 32);
        const short* As = lA[cur];
        const short* Bs = lB[cur];
        bf16x8 af[4], bfr[4];
        #pragma unroll
        for (int m = 0; m < 4; ++m)
            af[m] = *(const bf16x8*)&As[(row0 + m * 16 + lr) * 32 + kg8];
        #pragma unroll
        for (int n = 0; n < 4; ++n)
            bfr[n] = *(const bf16x8*)&Bs[(col0 + n * 16 + lr) * 32 + kg8];
        #pragma unroll
        for (int m = 0; m < 4; ++m)
            #pragma unroll
            for (int n = 0; n < 4; ++n)
                acc[m][n] = __builtin_amdgcn_mfma_f32_16x16x32_bf16(
                    af[m], bfr[n], acc[m][n], 0, 0, 0);
        __syncthreads();
        cur ^= 1;
    }
#undef STAGE

    // C/D layout: col = lane&15, row = (lane>>4)*4 + j
    #pragma unroll
    for (int n = 0; n < 4; ++n) {
        const int col = bn + col0 + n * 16 + (lane & 15);
        const float bv = bias[col];
        #pragma unroll
        for (int m = 0; m < 4; ++m) {
            const int rbase = bm + row0 + m * 16 + (lane >> 4) * 4;
            #pragma unroll
            for (int j = 0; j < 4; ++j) {
                const float v = acc[m][n][j] + bv;
                if (OUTBF) Cb[(size_t)(rbase + j) * N + col] = f2bf(v);
                else       Cf[(size_t)(rbase + j) * N + col] = v;
            }
        }
    }
}

// ---------------------------------------------------------------------------
// Feature map v2 (MFMA). grid: BH_*(T_/64) blocks, 256 thr (4 waves).
// Block handles 64 tokens x {q,k}. proj = (z @ omgT^T) * invnrm, then
// elementwise feature transform. LDS tiles padded to 72 shorts/row.
// ---------------------------------------------------------------------------
__global__ __launch_bounds__(256) void features_mfma(
    const short* __restrict__ qkvb,       // [B, T, 3C] bf16
    const short* __restrict__ omgH,       // [H][64f][64d] bf16 (hi)
    const short* __restrict__ omgL,       // [H][64f][64d] bf16 (lo)
    const float* __restrict__ qn,
    const float* __restrict__ qw,
    float* __restrict__ qf,               // [BH, T, 64]
    float* __restrict__ kf)
{
    __shared__ short zq[64][72];
    __shared__ short zk[64][72];
    __shared__ short omh[64][72];
    __shared__ short oml[64][72];
    __shared__ float invn[2][64];

    const int tid = threadIdx.x;
    const int bh  = blockIdx.x >> 6;      // 0..31
    const int tb  = blockIdx.x & 63;      // 0..63
    const int b   = bh >> 4, h = bh & 15;
    const int t0  = tb * 64;

    // load tiles: thread -> row = tid>>2, c0 = (tid&3)*16
    {
        const int row = tid >> 2;
        const int c0  = (tid & 3) * 16;
        const size_t zbase = ((size_t)(b * T_ + t0 + row)) * THREEC + h * HD + c0;
        const size_t obase = ((size_t)h * NFEAT + row) * HD + c0;
        *(bf16x8*)&zq[row][c0]      = *(const bf16x8*)&qkvb[zbase];
        *(bf16x8*)&zq[row][c0 + 8]  = *(const bf16x8*)&qkvb[zbase + 8];
        *(bf16x8*)&zk[row][c0]      = *(const bf16x8*)&qkvb[zbase + EMBED];
        *(bf16x8*)&zk[row][c0 + 8]  = *(const bf16x8*)&qkvb[zbase + EMBED + 8];
        *(bf16x8*)&omh[row][c0]     = *(const bf16x8*)&omgH[obase];
        *(bf16x8*)&omh[row][c0 + 8] = *(const bf16x8*)&omgH[obase + 8];
        *(bf16x8*)&oml[row][c0]     = *(const bf16x8*)&omgL[obase];
        *(bf16x8*)&oml[row][c0 + 8] = *(const bf16x8*)&omgL[obase + 8];
    }
    __syncthreads();

    // per-token inverse norms (from bf16 z, matching prior rounds)
    {
        const int t = tid >> 2;
        const int q = tid & 3;
        #pragma unroll
        for (int p = 0; p < 2; ++p) {
            const short* Z = p ? &zk[t][q * 16] : &zq[t][q * 16];
            float ss = 0.0f;
            #pragma unroll
            for (int j = 0; j < 16; ++j) { float v = bf2f(Z[j]); ss += v * v; }
            ss += __shfl_xor(ss, 1, 64);
            ss += __shfl_xor(ss, 2, 64);
            if (q == 0) invn[p][t] = 1.0f / fmaxf(sqrtf(ss), 1e-12f);
        }
    }
    __syncthreads();

    const int wave = tid >> 6;
    const int lane = tid & 63;
    const int p    = wave >> 1;           // 0 = q, 1 = k
    const int half = wave & 1;            // token half
    const short (*Z)[72] = p ? zk : zq;

    const float s0 = qn[0], s1 = qn[1];
    const float sq2s0 = sqrtf(2.0f * fmaxf(s0, 0.0f));
    const float sq2s1 = sqrtf(2.0f * fmaxf(s1, 0.0f));
    const float sc0 = sqrtf(fmaxf(qw[0], 0.0f)) * (1.0f / 32.0f);
    const float sc1 = sqrtf(fmaxf(qw[1], 0.0f)) * (1.0f / 32.0f);

    const int lr  = lane & 15;
    const int kg8 = (lane >> 4) * 8;

    f32x4 acc[2][4] = {};
    #pragma unroll
    for (int kk = 0; kk < 2; ++kk) {
        bf16x8 a[2], bh8[4], bl8[4];
        #pragma unroll
        for (int m = 0; m < 2; ++m)
            a[m] = *(const bf16x8*)&Z[half * 32 + m * 16 + lr][kk * 32 + kg8];
        #pragma unroll
        for (int n = 0; n < 4; ++n) {
            bh8[n] = *(const bf16x8*)&omh[n * 16 + lr][kk * 32 + kg8];
            bl8[n] = *(const bf16x8*)&oml[n * 16 + lr][kk * 32 + kg8];
        }
        #pragma unroll
        for (int m = 0; m < 2; ++m)
            #pragma unroll
            for (int n = 0; n < 4; ++n) {
                acc[m][n] = __builtin_amdgcn_mfma_f32_16x16x32_bf16(
                    a[m], bh8[n], acc[m][n], 0, 0, 0);
                acc[m][n] = __builtin_amdgcn_mfma_f32_16x16x32_bf16(
                    a[m], bl8[n], acc[m][n], 0, 0, 0);
            }
    }

    float* dstbase = (p ? kf : qf) + ((size_t)bh * T_ + t0) * NFEAT;
    #pragma unroll
    for (int n = 0; n < 4; ++n) {
        const int f = n * 16 + (lane & 15);
        const float s_r   = (n < 2) ? s0 : s1;
        const float sq2s  = (n < 2) ? sq2s0 : sq2s1;
        const float scale = (n < 2) ? sc0 : sc1;
        #pragma unroll
        for (int m = 0; m < 2; ++m) {
            const int tb4 = half * 32 + m * 16 + (lane >> 4) * 4;
            #pragma unroll
            for (int j = 0; j < 4; ++j) {
                const int t = tb4 + j;
                const float proj = acc[m][n][j] * invn[p][t];
                const float arg = fminf(fmaxf(proj * sq2s - s_r, -20.0f), 20.0f);
                const float val = proj * proj * __expf(arg) * scale;
                dstbase[(size_t)t * NFEAT + f] = val;
            }
        }
    }
}

// ---------------------------------------------------------------------------
// Per-chunk KV sums
// ---------------------------------------------------------------------------
__global__ __launch_bounds__(256) void chunk_sums(
    const float* __restrict__ kf,
    const short* __restrict__ qkvb,
    float* __restrict__ cKV,              // [BH*NC, 64, 64]
    float* __restrict__ cK)               // [BH*NC, 64]
{
    __shared__ float kfs[L_][NFEAT];
    __shared__ float vs[L_][HD];
    const int tid = threadIdx.x;
    const int chunk = blockIdx.x;
    const int bh = chunk / NC_, c = chunk % NC_;
    const int b = bh >> 4, h = bh & 15;
    const int t0 = c * L_;

    for (int i = tid; i < L_ * NFEAT; i += 256) {
        const int t = i >> 6, f = i & 63;
        kfs[t][f] = kf[((size_t)bh * T_ + t0 + t) * NFEAT + f];
        vs[t][f]  = bf2f(qkvb[((size_t)(b * T_ + t0 + t)) * THREEC + 2 * EMBED + h * HD + f]);
    }
    __syncthreads();

    const int f  = tid >> 2;
    const int d0 = (tid & 3) * 16;
    float acc[16] = {};
    float ks = 0.0f;
    for (int t = 0; t < L_; ++t) {
        const float kft = kfs[t][f];
        ks += kft;
        #pragma unroll
        for (int j = 0; j < 16; ++j) acc[j] += kft * vs[t][d0 + j];
    }
    float* dst = cKV + (size_t)chunk * NFEAT * HD + f * HD + d0;
    #pragma unroll
    for (int j = 0; j < 16; ++j) dst[j] = acc[j];
    if ((tid & 3) == 0) cK[(size_t)chunk * NFEAT + f] = ks;
}

// ---------------------------------------------------------------------------
// Exclusive prefix over chunks
// ---------------------------------------------------------------------------
__global__ __launch_bounds__(256) void prefix_scan(
    float* __restrict__ cKV, float* __restrict__ cK)
{
    const int bh = blockIdx.x;
    const int tid = threadIdx.x;
    float pref[16];
    #pragma unroll
    for (int j = 0; j < 16; ++j) pref[j] = 0.0f;
    float prefk = 0.0f;
    for (int c = 0; c < NC_; ++c) {
        float* base = cKV + ((size_t)bh * NC_ + c) * (NFEAT * HD) + tid * 16;
        float4* b4 = reinterpret_cast<float4*>(base);
        float tmp[16];
        #pragma unroll
        for (int q = 0; q < 4; ++q) {
            float4 v = b4[q];
            tmp[q * 4 + 0] = v.x; tmp[q * 4 + 1] = v.y;
            tmp[q * 4 + 2] = v.z; tmp[q * 4 + 3] = v.w;
        }
        #pragma unroll
        for (int q = 0; q < 4; ++q) {
            float4 v;
            v.x = pref[q * 4 + 0]; v.y = pref[q * 4 + 1];
            v.z = pref[q * 4 + 2]; v.w = pref[q * 4 + 3];
            b4[q] = v;
        }
        #pragma unroll
        for (int j = 0; j < 16; ++j) pref[j] += tmp[j];
        if (tid < 64) {
            float* kb = cK + ((size_t)bh * NC_ + c) * NFEAT + tid;
            const float tk = *kb;
            *kb = prefk;
            prefk += tk;
        }
    }
}

// ---------------------------------------------------------------------------
// Intra-chunk causal attention; writes bf16 attn output [B*T, C]
// ---------------------------------------------------------------------------
__global__ __launch_bounds__(256) void intra_attn(
    const float* __restrict__ qf,
    const float* __restrict__ kf,
    const short* __restrict__ qkvb,       // v region read (bf16)
    const float* __restrict__ cKV,
    const float* __restrict__ cK,
    short* __restrict__ attnb)            // [B*T, EMBED] bf16
{
    __shared__ float Qs[L_][NFEAT];
    __shared__ float Ks[L_][NFEAT];       // phase 2: reused for KVprefix
    __shared__ float Vs[L_][HD];
    __shared__ float At[L_][L_];
    const int tid = threadIdx.x;
    const int chunk = blockIdx.x;
    const int bh = chunk / NC_, c = chunk % NC_;
    const int b = bh >> 4, h = bh & 15;
    const int t0 = c * L_;

    for (int i = tid; i < L_ * NFEAT; i += 256) {
        const int t = i >> 6, f = i & 63;
        Qs[t][f] = qf[((size_t)bh * T_ + t0 + t) * NFEAT + f];
        Ks[t][f] = kf[((size_t)bh * T_ + t0 + t) * NFEAT + f];
        Vs[t][f] = bf2f(qkvb[((size_t)(b * T_ + t0 + t)) * THREEC + 2 * EMBED + h * HD + f]);
    }
    __syncthreads();

    const int t = tid >> 2;
    const int g = tid & 3;

    float rowsum = 0.0f;
    const float4* qrow = reinterpret_cast<const float4*>(&Qs[t][0]);
    for (int si = 0; si < 16; ++si) {
        const int s = g * 16 + si;
        float a = 0.0f;
        if (s <= t) {
            const float4* krow = reinterpret_cast<const float4*>(&Ks[s][0]);
            #pragma unroll
            for (int f4 = 0; f4 < 16; ++f4) {
                const float4 qa = qrow[f4];
                const float4 kb = krow[f4];
                a += qa.x * kb.x + qa.y * kb.y + qa.z * kb.z + qa.w * kb.w;
            }
        }
        At[s][t] = a;
        rowsum += a;
    }
    rowsum += __shfl_xor(rowsum, 1, 64);
    rowsum += __shfl_xor(rowsum, 2, 64);
    __syncthreads();

    for (int i = tid; i < NFEAT * HD; i += 256) {
        reinterpret_cast<float*>(Ks)[i] = cKV[(size_t)chunk * (NFEAT * HD) + i];
    }
    __syncthreads();

    const int d0 = g * 16;
    float acc[16] = {};
    for (int s = 0; s < L_; ++s) {
        const float a = At[s][t];
        #pragma unroll
        for (int j = 0; j < 16; ++j) acc[j] += a * Vs[s][d0 + j];
    }
    float qkp = 0.0f;
    const float* kp = cK + (size_t)chunk * NFEAT;
    for (int f = 0; f < 64; ++f) {
        const float qtf = Qs[t][f];
        qkp += qtf * kp[f];
        #pragma unroll
        for (int j = 0; j < 16; ++j) acc[j] += qtf * Ks[f][d0 + j];
    }
    const float den = fmaxf(rowsum + qkp, 1e-6f);
    const float invden = 1.0f / den;

    bf16x8 o0, o1;
    #pragma unroll
    for (int j = 0; j < 8; ++j) {
        o0[j] = f2bf(acc[j] * invden);
        o1[j] = f2bf(acc[8 + j] * invden);
    }
    bf16x8* dst = (bf16x8*)(attnb + ((size_t)(b * T_ + t0 + t)) * EMBED + h * HD + d0);
    dst[0] = o0;
    dst[1] = o1;
}

// ---------------------------------------------------------------------------
extern "C" void kernel_launch(void* const* d_in, const int* in_sizes, int n_in,
                              void* d_out, int out_size, void* d_ws, size_t ws_size,
                              hipStream_t stream)
{
    const float* x     = (const float*)d_in[0];
    const float* w_qkv = (const float*)d_in[1];
    const float* b_qkv = (const float*)d_in[2];
    const float* w_out = (const float*)d_in[3];
    const float* b_out = (const float*)d_in[4];
    const float* omega = (const float*)d_in[5];
    const float* qn    = (const float*)d_in[6];
    const float* qw    = (const float*)d_in[7];
    float* out = (float*)d_out;

    // workspace layout
    short* xb    = (short*)d_ws;               //  8,388,608
    short* wqb   = xb    + 8388608;            //  3,145,728
    short* wob   = wqb   + 3145728;            //  1,048,576
    short* qkvb  = wob   + 1048576;            // 25,165,824
    short* attnb = qkvb  + 25165824;           //  8,388,608
    short* omgH  = attnb + 8388608;            //     65,536
    short* omgL  = omgH  + 65536;              //     65,536
    float* qf    = (float*)(omgL + 65536);     //  8,388,608
    float* kf    = qf  + 8388608;
    float* cKV   = kf  + 8388608;              //  8,388,608
    float* cK    = cKV + 8388608;              //    131,072

    const int M = B_ * T_;   // 8192

    // casts + omega prep
    cast_kernel<<<dim3(8388608 / 8 / 256), 256, 0, stream>>>(x, xb, 8388608 / 8);
    cast_kernel<<<dim3(3145728 / 8 / 256), 256, 0, stream>>>(w_qkv, wqb, 3145728 / 8);
    cast_kernel<<<dim3(1048576 / 8 / 256), 256, 0, stream>>>(w_out, wob, 1048576 / 8);
    omega_prep<<<dim3(256), 256, 0, stream>>>(omega, omgH, omgL);

    // 1. qkv = x @ w_qkv^T + b_qkv  (bf16 out)
    gemm_bf16<1><<<dim3(THREEC / 128, M / 128), 256, 0, stream>>>(
        xb, wqb, b_qkv, nullptr, qkvb, M, THREEC, EMBED);
    // 2. features (MFMA)
    features_mfma<<<dim3(BH_ * (T_ / 64)), 256, 0, stream>>>(
        qkvb, omgH, omgL, qn, qw, qf, kf);
    // 3. per-chunk KV sums
    chunk_sums<<<dim3(BH_ * NC_), 256, 0, stream>>>(kf, qkvb, cKV, cK);
    // 4. exclusive prefix over chunks
    prefix_scan<<<dim3(BH_), 256, 0, stream>>>(cKV, cK);
    // 5. intra-chunk attention -> bf16 attn [B*T, C]
    intra_attn<<<dim3(BH_ * NC_), 256, 0, stream>>>(qf, kf, qkvb, cKV, cK, attnb);
    // 6. out = attn @ w_out^T + b_out (fp32 out)
    gemm_bf16<0><<<dim3(EMBED / 128, M / 128), 256, 0, stream>>>(
        attnb, wob, b_out, out, nullptr, M, EMBED, EMBED);
}

// Round 4
// 194.405 us; speedup vs baseline: 6.8527x; 1.9031x over previous
//
#include <hip/hip_runtime.h>
#include <math.h>

#define EMBED   1024
#define THREEC  3072
#define NH      16
#define HD      64
#define NFEAT   64      // R * M = 2 * 32
#define RN      2
#define MM_     32
#define B_      2
#define T_      4096
#define L_      64      // chunk length
#define NC_     64      // T_ / L_
#define BH_     32      // B_ * NH

typedef __attribute__((ext_vector_type(8))) short bf16x8;
typedef __attribute__((ext_vector_type(4))) float f32x4;

__device__ __forceinline__ float bf2f(short s) {
    unsigned u = ((unsigned)(unsigned short)s) << 16;
    return __builtin_bit_cast(float, u);
}
__device__ __forceinline__ short f2bf(float f) {
    unsigned u = __builtin_bit_cast(unsigned, f);
    u += 0x7fff + ((u >> 16) & 1);
    return (short)(u >> 16);
}
__device__ __forceinline__ void gload16(const short* g, short* l) {
    __builtin_amdgcn_global_load_lds(
        (const __attribute__((address_space(1))) void*)g,
        (__attribute__((address_space(3))) void*)l, 16, 0, 0);
}

// ---------------------------------------------------------------------------
// f32 -> bf16 cast, 8 elems/thread
// ---------------------------------------------------------------------------
__global__ __launch_bounds__(256) void cast_kernel(
    const float* __restrict__ in, short* __restrict__ out, int n8)
{
    int i = blockIdx.x * 256 + threadIdx.x;
    if (i >= n8) return;
    const float4* p = (const float4*)in + (size_t)i * 2;
    float4 a = p[0], b = p[1];
    bf16x8 o = { f2bf(a.x), f2bf(a.y), f2bf(a.z), f2bf(a.w),
                 f2bf(b.x), f2bf(b.y), f2bf(b.z), f2bf(b.w) };
    *((bf16x8*)out + i) = o;
}

// ---------------------------------------------------------------------------
// omega [R,H,D,M] fp32 -> omgT[h][f=r*32+m][d] bf16 hi/lo split
// ---------------------------------------------------------------------------
__global__ __launch_bounds__(256) void omega_prep(
    const float* __restrict__ omega, short* __restrict__ hi, short* __restrict__ lo)
{
    int i = blockIdx.x * 256 + threadIdx.x;   // over H*F*D = 65536
    if (i >= NH * NFEAT * HD) return;
    int d = i & 63;
    int f = (i >> 6) & 63;
    int h = i >> 12;
    int r = f >> 5, m = f & 31;
    float w = omega[(((size_t)(r * NH + h) * HD + d) * MM_) + m];
    short a = f2bf(w);
    hi[i] = a;
    lo[i] = f2bf(w - bf2f(a));
}

// ---------------------------------------------------------------------------
// bf16 MFMA GEMM (m97 structure)
// ---------------------------------------------------------------------------
template<int OUTBF>
__global__ __launch_bounds__(256) void gemm_bf16(
    const short* __restrict__ A,      // [M][K] bf16
    const short* __restrict__ W,      // [N][K] bf16
    const float* __restrict__ bias,   // [N]
    float* __restrict__ Cf, short* __restrict__ Cb,
    int M, int N, int K)
{
    __shared__ short lA[2][128 * 32];
    __shared__ short lB[2][128 * 32];
    const int tid  = threadIdx.x;
    const int bm   = blockIdx.y * 128;
    const int bn   = blockIdx.x * 128;
    const int lane = tid & 63;
    const int wave = tid >> 6;
    const int row0 = (wave >> 1) * 64;
    const int col0 = (wave & 1) * 64;
    const int lr   = lane & 15;
    const int kg8  = (lane >> 4) * 8;

    f32x4 acc[4][4] = {};

#define STAGE(buf, k0)                                                        \
    {                                                                         \
        _Pragma("unroll")                                                     \
        for (int i = 0; i < 2; ++i) {                                         \
            int idx = i * 256 + tid;                                          \
            int row = idx >> 2, kq = (idx & 3) * 8;                           \
            gload16(&A[(size_t)(bm + row) * K + (k0) + kq], &lA[buf][idx * 8]); \
            gload16(&W[(size_t)(bn + row) * K + (k0) + kq], &lB[buf][idx * 8]); \
        }                                                                     \
    }

    const int KT = K >> 5;
    STAGE(0, 0);
    __syncthreads();
    int cur = 0;
    for (int kt = 0; kt < KT; ++kt) {
        if (kt + 1 < KT) STAGE(cur ^ 1, (kt + 1) * 32);
        const short* As = lA[cur];
        const short* Bs = lB[cur];
        bf16x8 af[4], bfr[4];
        #pragma unroll
        for (int m = 0; m < 4; ++m)
            af[m] = *(const bf16x8*)&As[(row0 + m * 16 + lr) * 32 + kg8];
        #pragma unroll
        for (int n = 0; n < 4; ++n)
            bfr[n] = *(const bf16x8*)&Bs[(col0 + n * 16 + lr) * 32 + kg8];
        #pragma unroll
        for (int m = 0; m < 4; ++m)
            #pragma unroll
            for (int n = 0; n < 4; ++n)
                acc[m][n] = __builtin_amdgcn_mfma_f32_16x16x32_bf16(
                    af[m], bfr[n], acc[m][n], 0, 0, 0);
        __syncthreads();
        cur ^= 1;
    }
#undef STAGE

    #pragma unroll
    for (int n = 0; n < 4; ++n) {
        const int col = bn + col0 + n * 16 + (lane & 15);
        const float bv = bias[col];
        #pragma unroll
        for (int m = 0; m < 4; ++m) {
            const int rbase = bm + row0 + m * 16 + (lane >> 4) * 4;
            #pragma unroll
            for (int j = 0; j < 4; ++j) {
                const float v = acc[m][n][j] + bv;
                if (OUTBF) Cb[(size_t)(rbase + j) * N + col] = f2bf(v);
                else       Cf[(size_t)(rbase + j) * N + col] = v;
            }
        }
    }
}

// ---------------------------------------------------------------------------
// Feature map (MFMA), now writing bf16 qf/kf.
// ---------------------------------------------------------------------------
__global__ __launch_bounds__(256) void features_mfma(
    const short* __restrict__ qkvb,       // [B, T, 3C] bf16
    const short* __restrict__ omgH,       // [H][64f][64d] bf16 (hi)
    const short* __restrict__ omgL,       // [H][64f][64d] bf16 (lo)
    const float* __restrict__ qn,
    const float* __restrict__ qw,
    short* __restrict__ qf,               // [BH, T, 64] bf16
    short* __restrict__ kf)
{
    __shared__ short zq[64][72];
    __shared__ short zk[64][72];
    __shared__ short omh[64][72];
    __shared__ short oml[64][72];
    __shared__ float invn[2][64];

    const int tid = threadIdx.x;
    const int bh  = blockIdx.x >> 6;      // 0..31
    const int tb  = blockIdx.x & 63;      // 0..63
    const int b   = bh >> 4, h = bh & 15;
    const int t0  = tb * 64;

    {
        const int row = tid >> 2;
        const int c0  = (tid & 3) * 16;
        const size_t zbase = ((size_t)(b * T_ + t0 + row)) * THREEC + h * HD + c0;
        const size_t obase = ((size_t)h * NFEAT + row) * HD + c0;
        *(bf16x8*)&zq[row][c0]      = *(const bf16x8*)&qkvb[zbase];
        *(bf16x8*)&zq[row][c0 + 8]  = *(const bf16x8*)&qkvb[zbase + 8];
        *(bf16x8*)&zk[row][c0]      = *(const bf16x8*)&qkvb[zbase + EMBED];
        *(bf16x8*)&zk[row][c0 + 8]  = *(const bf16x8*)&qkvb[zbase + EMBED + 8];
        *(bf16x8*)&omh[row][c0]     = *(const bf16x8*)&omgH[obase];
        *(bf16x8*)&omh[row][c0 + 8] = *(const bf16x8*)&omgH[obase + 8];
        *(bf16x8*)&oml[row][c0]     = *(const bf16x8*)&omgL[obase];
        *(bf16x8*)&oml[row][c0 + 8] = *(const bf16x8*)&omgL[obase + 8];
    }
    __syncthreads();

    {
        const int t = tid >> 2;
        const int q = tid & 3;
        #pragma unroll
        for (int p = 0; p < 2; ++p) {
            const short* Z = p ? &zk[t][q * 16] : &zq[t][q * 16];
            float ss = 0.0f;
            #pragma unroll
            for (int j = 0; j < 16; ++j) { float v = bf2f(Z[j]); ss += v * v; }
            ss += __shfl_xor(ss, 1, 64);
            ss += __shfl_xor(ss, 2, 64);
            if (q == 0) invn[p][t] = 1.0f / fmaxf(sqrtf(ss), 1e-12f);
        }
    }
    __syncthreads();

    const int wave = tid >> 6;
    const int lane = tid & 63;
    const int p    = wave >> 1;           // 0 = q, 1 = k
    const int half = wave & 1;            // token half
    const short (*Z)[72] = p ? zk : zq;

    const float s0 = qn[0], s1 = qn[1];
    const float sq2s0 = sqrtf(2.0f * fmaxf(s0, 0.0f));
    const float sq2s1 = sqrtf(2.0f * fmaxf(s1, 0.0f));
    const float sc0 = sqrtf(fmaxf(qw[0], 0.0f)) * (1.0f / 32.0f);
    const float sc1 = sqrtf(fmaxf(qw[1], 0.0f)) * (1.0f / 32.0f);

    const int lr  = lane & 15;
    const int kg8 = (lane >> 4) * 8;

    f32x4 acc[2][4] = {};
    #pragma unroll
    for (int kk = 0; kk < 2; ++kk) {
        bf16x8 a[2], bh8[4], bl8[4];
        #pragma unroll
        for (int m = 0; m < 2; ++m)
            a[m] = *(const bf16x8*)&Z[half * 32 + m * 16 + lr][kk * 32 + kg8];
        #pragma unroll
        for (int n = 0; n < 4; ++n) {
            bh8[n] = *(const bf16x8*)&omh[n * 16 + lr][kk * 32 + kg8];
            bl8[n] = *(const bf16x8*)&oml[n * 16 + lr][kk * 32 + kg8];
        }
        #pragma unroll
        for (int m = 0; m < 2; ++m)
            #pragma unroll
            for (int n = 0; n < 4; ++n) {
                acc[m][n] = __builtin_amdgcn_mfma_f32_16x16x32_bf16(
                    a[m], bh8[n], acc[m][n], 0, 0, 0);
                acc[m][n] = __builtin_amdgcn_mfma_f32_16x16x32_bf16(
                    a[m], bl8[n], acc[m][n], 0, 0, 0);
            }
    }

    short* dstbase = (p ? kf : qf) + ((size_t)bh * T_ + t0) * NFEAT;
    #pragma unroll
    for (int n = 0; n < 4; ++n) {
        const int f = n * 16 + (lane & 15);
        const float s_r   = (n < 2) ? s0 : s1;
        const float sq2s  = (n < 2) ? sq2s0 : sq2s1;
        const float scale = (n < 2) ? sc0 : sc1;
        #pragma unroll
        for (int m = 0; m < 2; ++m) {
            const int tb4 = half * 32 + m * 16 + (lane >> 4) * 4;
            #pragma unroll
            for (int j = 0; j < 4; ++j) {
                const int t = tb4 + j;
                const float proj = acc[m][n][j] * invn[p][t];
                const float arg = fminf(fmaxf(proj * sq2s - s_r, -20.0f), 20.0f);
                const float val = proj * proj * __expf(arg) * scale;
                dstbase[(size_t)t * NFEAT + f] = f2bf(val);
            }
        }
    }
}

// ---------------------------------------------------------------------------
// Per-chunk KV sums. Writes cKV TRANSPOSED: [chunk][d][f] = S[f][d].
// ---------------------------------------------------------------------------
__global__ __launch_bounds__(256) void chunk_sums(
    const short* __restrict__ kf,         // bf16
    const short* __restrict__ qkvb,
    float* __restrict__ cKV,              // [BH*NC, 64d, 64f]
    float* __restrict__ cK)               // [BH*NC, 64]
{
    __shared__ float kfs[64][64];
    __shared__ float vs[64][64];
    float (*st)[65] = (float(*)[65])kfs;  // reuse after compute (overlaps vs head)

    const int tid = threadIdx.x;
    const int chunk = blockIdx.x;
    const int bh = chunk >> 6, c = chunk & 63;
    const int b = bh >> 4, h = bh & 15;
    const int t0 = c * L_;

    {
        const int row = tid >> 2;
        const int c0  = (tid & 3) * 16;
        const short* krow = kf + ((size_t)bh * T_ + t0 + row) * NFEAT;
        const short* vrow = qkvb + ((size_t)(b * T_ + t0 + row)) * THREEC + 2 * EMBED + h * HD;
        bf16x8 k0 = *(const bf16x8*)&krow[c0], k1 = *(const bf16x8*)&krow[c0 + 8];
        bf16x8 v0 = *(const bf16x8*)&vrow[c0], v1 = *(const bf16x8*)&vrow[c0 + 8];
        #pragma unroll
        for (int j = 0; j < 8; ++j) {
            kfs[row][c0 + j]     = bf2f(k0[j]);
            kfs[row][c0 + 8 + j] = bf2f(k1[j]);
            vs[row][c0 + j]      = bf2f(v0[j]);
            vs[row][c0 + 8 + j]  = bf2f(v1[j]);
        }
    }
    __syncthreads();

    const int f  = tid >> 2;
    const int d0 = (tid & 3) * 16;
    float acc[16] = {};
    float ks = 0.0f;
    for (int t = 0; t < L_; ++t) {
        const float kft = kfs[t][f];
        ks += kft;
        #pragma unroll
        for (int j = 0; j < 16; ++j) acc[j] += kft * vs[t][d0 + j];
    }
    if ((tid & 3) == 0) cK[(size_t)chunk * NFEAT + f] = ks;
    __syncthreads();   // done reading kfs/vs

    #pragma unroll
    for (int j = 0; j < 16; ++j) st[f][d0 + j] = acc[j];
    __syncthreads();

    // coalesced transposed write: thread i -> [d][f] linear i*16..i*16+15
    {
        const int d  = tid >> 2;
        const int f0 = (tid & 3) * 16;
        float* dst = cKV + (size_t)chunk * (NFEAT * HD) + tid * 16;
        #pragma unroll
        for (int q = 0; q < 4; ++q) {
            float4 o;
            o.x = st[f0 + q * 4 + 0][d];
            o.y = st[f0 + q * 4 + 1][d];
            o.z = st[f0 + q * 4 + 2][d];
            o.w = st[f0 + q * 4 + 3][d];
            *(float4*)&dst[q * 4] = o;
        }
    }
}

// ---------------------------------------------------------------------------
// Exclusive prefix over chunks. grid: BH_*4 blocks; depth-2 prefetch.
// ---------------------------------------------------------------------------
__global__ __launch_bounds__(256) void prefix_scan(
    float* __restrict__ cKV, float* __restrict__ cK)
{
    const int bh  = blockIdx.x >> 2;
    const int sl  = blockIdx.x & 3;
    const int tid = threadIdx.x;
    float4* base = (float4*)(cKV + (size_t)bh * NC_ * (NFEAT * HD) + sl * 1024) + tid;
    float4 n0 = base[0];
    float4 n1 = base[1024];
    float4 pref; pref.x = pref.y = pref.z = pref.w = 0.0f;
    for (int c = 0; c < NC_; ++c) {
        float4 cur = n0;
        n0 = n1;
        if (c + 2 < NC_) n1 = base[(size_t)(c + 2) * 1024];
        else { n1.x = n1.y = n1.z = n1.w = 0.0f; }
        base[(size_t)c * 1024] = pref;
        pref.x += cur.x; pref.y += cur.y; pref.z += cur.z; pref.w += cur.w;
    }
    if (sl == 0 && tid < 64) {
        float* kb = cK + (size_t)bh * NC_ * NFEAT + tid;
        float m0 = kb[0];
        float m1 = kb[64];
        float p = 0.0f;
        for (int c = 0; c < NC_; ++c) {
            float cu = m0;
            m0 = m1;
            m1 = (c + 2 < NC_) ? kb[(size_t)(c + 2) * 64] : 0.0f;
            kb[(size_t)c * 64] = p;
            p += cu;
        }
    }
}

// ---------------------------------------------------------------------------
// Intra-chunk causal attention via MFMA. 4 waves, each owns a 16-row band.
// ---------------------------------------------------------------------------
__global__ __launch_bounds__(256) void intra_mfma(
    const short* __restrict__ qf,         // [BH,T,64] bf16
    const short* __restrict__ kf,
    const short* __restrict__ qkvb,       // v region (bf16)
    const float* __restrict__ cKV,        // [chunk][d][f] prefix fp32
    const float* __restrict__ cK,         // [chunk][f] prefix fp32
    short* __restrict__ attnb)            // [B*T, EMBED] bf16
{
    __shared__ short Qs[64][72];
    __shared__ short Ks[64][72];
    __shared__ short Vt[64][72];          // V^T: [d][t]
    __shared__ short Pp[64][72];          // KVp^T: [d][f]
    __shared__ short At[64][72];          // masked A: [t][s]
    __shared__ float rs_l[64], qkp_l[64], cKp[64];

    const int tid = threadIdx.x;
    const int chunk = blockIdx.x;
    const int bh = chunk >> 6, c = chunk & 63;
    const int b = bh >> 4, h = bh & 15;
    const int t0 = c * L_;

    // ---- load phase ----
    {
        const int row = tid >> 2;
        const int c0  = (tid & 3) * 16;
        const short* qrow = qf + ((size_t)bh * T_ + t0 + row) * NFEAT;
        const short* krow = kf + ((size_t)bh * T_ + t0 + row) * NFEAT;
        const short* vrow = qkvb + ((size_t)(b * T_ + t0 + row)) * THREEC + 2 * EMBED + h * HD;
        *(bf16x8*)&Qs[row][c0]     = *(const bf16x8*)&qrow[c0];
        *(bf16x8*)&Qs[row][c0 + 8] = *(const bf16x8*)&qrow[c0 + 8];
        *(bf16x8*)&Ks[row][c0]     = *(const bf16x8*)&krow[c0];
        *(bf16x8*)&Ks[row][c0 + 8] = *(const bf16x8*)&krow[c0 + 8];
        bf16x8 v0 = *(const bf16x8*)&vrow[c0], v1 = *(const bf16x8*)&vrow[c0 + 8];
        #pragma unroll
        for (int j = 0; j < 8; ++j) {
            Vt[c0 + j][row]     = v0[j];
            Vt[c0 + 8 + j][row] = v1[j];
        }
        // KVp^T: linear [d][f], d=row, f0=c0
        const float* pbase = cKV + (size_t)chunk * (NFEAT * HD) + tid * 16;
        float4 p0 = *(const float4*)&pbase[0],  p1 = *(const float4*)&pbase[4];
        float4 p2 = *(const float4*)&pbase[8],  p3 = *(const float4*)&pbase[12];
        bf16x8 o0 = { f2bf(p0.x), f2bf(p0.y), f2bf(p0.z), f2bf(p0.w),
                      f2bf(p1.x), f2bf(p1.y), f2bf(p1.z), f2bf(p1.w) };
        bf16x8 o1 = { f2bf(p2.x), f2bf(p2.y), f2bf(p2.z), f2bf(p2.w),
                      f2bf(p3.x), f2bf(p3.y), f2bf(p3.z), f2bf(p3.w) };
        *(bf16x8*)&Pp[row][c0]     = o0;
        *(bf16x8*)&Pp[row][c0 + 8] = o1;
        if (tid < 64) cKp[tid] = cK[(size_t)chunk * NFEAT + tid];
    }
    __syncthreads();

    const int wave = tid >> 6;
    const int lane = tid & 63;
    const int lr   = lane & 15;
    const int kg   = (lane >> 4) * 8;
    const int r0   = wave * 16;

    // ---- phase A: A = Qf @ Kf^T, mask, rowsum, store bf16 ----
    bf16x8 aq[2];
    aq[0] = *(const bf16x8*)&Qs[r0 + lr][kg];
    aq[1] = *(const bf16x8*)&Qs[r0 + lr][32 + kg];
    f32x4 accA[4] = {};
    #pragma unroll
    for (int n = 0; n < 4; ++n) {
        accA[n] = __builtin_amdgcn_mfma_f32_16x16x32_bf16(
            aq[0], *(const bf16x8*)&Ks[n * 16 + lr][kg], accA[n], 0, 0, 0);
        accA[n] = __builtin_amdgcn_mfma_f32_16x16x32_bf16(
            aq[1], *(const bf16x8*)&Ks[n * 16 + lr][32 + kg], accA[n], 0, 0, 0);
    }
    float rsum[4] = {0.0f, 0.0f, 0.0f, 0.0f};
    #pragma unroll
    for (int n = 0; n < 4; ++n) {
        const int s = n * 16 + lr;
        #pragma unroll
        for (int j = 0; j < 4; ++j) {
            const int t = r0 + (lane >> 4) * 4 + j;
            const float a = (s <= t) ? accA[n][j] : 0.0f;
            rsum[j] += a;
            At[t][s] = f2bf(a);
        }
    }
    #pragma unroll
    for (int j = 0; j < 4; ++j) {
        rsum[j] += __shfl_xor(rsum[j], 1, 64);
        rsum[j] += __shfl_xor(rsum[j], 2, 64);
        rsum[j] += __shfl_xor(rsum[j], 4, 64);
        rsum[j] += __shfl_xor(rsum[j], 8, 64);
    }
    if (lr == 0) {
        #pragma unroll
        for (int j = 0; j < 4; ++j) rs_l[r0 + (lane >> 4) * 4 + j] = rsum[j];
    }

    // qkp[t] = Qf[t] . kp  (fp32)
    {
        const int t  = tid >> 2;
        const int fq = (tid & 3) * 16;
        float s = 0.0f;
        #pragma unroll
        for (int j = 0; j < 16; ++j) s += bf2f(Qs[t][fq + j]) * cKp[fq + j];
        s += __shfl_xor(s, 1, 64);
        s += __shfl_xor(s, 2, 64);
        if ((tid & 3) == 0) qkp_l[t] = s;
    }
    __syncthreads();

    // ---- phase B: out = A@V + Qf@KVp^T ----
    bf16x8 aa[2];
    aa[0] = *(const bf16x8*)&At[r0 + lr][kg];
    aa[1] = *(const bf16x8*)&At[r0 + lr][32 + kg];
    f32x4 acc[4] = {};
    #pragma unroll
    for (int n = 0; n < 4; ++n) {
        acc[n] = __builtin_amdgcn_mfma_f32_16x16x32_bf16(
            aa[0], *(const bf16x8*)&Vt[n * 16 + lr][kg], acc[n], 0, 0, 0);
        acc[n] = __builtin_amdgcn_mfma_f32_16x16x32_bf16(
            aa[1], *(const bf16x8*)&Vt[n * 16 + lr][32 + kg], acc[n], 0, 0, 0);
        acc[n] = __builtin_amdgcn_mfma_f32_16x16x32_bf16(
            aq[0], *(const bf16x8*)&Pp[n * 16 + lr][kg], acc[n], 0, 0, 0);
        acc[n] = __builtin_amdgcn_mfma_f32_16x16x32_bf16(
            aq[1], *(const bf16x8*)&Pp[n * 16 + lr][32 + kg], acc[n], 0, 0, 0);
    }

    float inv[4];
    #pragma unroll
    for (int j = 0; j < 4; ++j) {
        const int t = r0 + (lane >> 4) * 4 + j;
        inv[j] = 1.0f / fmaxf(rs_l[t] + qkp_l[t], 1e-6f);
    }
    #pragma unroll
    for (int n = 0; n < 4; ++n) {
        const int d = n * 16 + lr;
        #pragma unroll
        for (int j = 0; j < 4; ++j) {
            const int t = r0 + (lane >> 4) * 4 + j;
            attnb[((size_t)(b * T_ + t0 + t)) * EMBED + h * HD + d] =
                f2bf(acc[n][j] * inv[j]);
        }
    }
}

// ---------------------------------------------------------------------------
extern "C" void kernel_launch(void* const* d_in, const int* in_sizes, int n_in,
                              void* d_out, int out_size, void* d_ws, size_t ws_size,
                              hipStream_t stream)
{
    const float* x     = (const float*)d_in[0];
    const float* w_qkv = (const float*)d_in[1];
    const float* b_qkv = (const float*)d_in[2];
    const float* w_out = (const float*)d_in[3];
    const float* b_out = (const float*)d_in[4];
    const float* omega = (const float*)d_in[5];
    const float* qn    = (const float*)d_in[6];
    const float* qw    = (const float*)d_in[7];
    float* out = (float*)d_out;

    // workspace layout (shorts first, then floats)
    short* xb    = (short*)d_ws;               //  8,388,608
    short* wqb   = xb    + 8388608;            //  3,145,728
    short* wob   = wqb   + 3145728;            //  1,048,576
    short* qkvb  = wob   + 1048576;            // 25,165,824
    short* attnb = qkvb  + 25165824;           //  8,388,608
    short* omgH  = attnb + 8388608;            //     65,536
    short* omgL  = omgH  + 65536;              //     65,536
    short* qfb   = omgL  + 65536;              //  8,388,608
    short* kfb   = qfb   + 8388608;            //  8,388,608
    float* cKV   = (float*)(kfb + 8388608);    //  8,388,608 floats
    float* cK    = cKV + 8388608;              //    131,072 floats

    const int M = B_ * T_;   // 8192

    cast_kernel<<<dim3(8388608 / 8 / 256), 256, 0, stream>>>(x, xb, 8388608 / 8);
    cast_kernel<<<dim3(3145728 / 8 / 256), 256, 0, stream>>>(w_qkv, wqb, 3145728 / 8);
    cast_kernel<<<dim3(1048576 / 8 / 256), 256, 0, stream>>>(w_out, wob, 1048576 / 8);
    omega_prep<<<dim3(256), 256, 0, stream>>>(omega, omgH, omgL);

    // 1. qkv = x @ w_qkv^T + b_qkv  (bf16 out)
    gemm_bf16<1><<<dim3(THREEC / 128, M / 128), 256, 0, stream>>>(
        xb, wqb, b_qkv, nullptr, qkvb, M, THREEC, EMBED);
    // 2. features (MFMA, bf16 out)
    features_mfma<<<dim3(BH_ * (T_ / 64)), 256, 0, stream>>>(
        qkvb, omgH, omgL, qn, qw, qfb, kfb);
    // 3. per-chunk KV sums (transposed cKV)
    chunk_sums<<<dim3(BH_ * NC_), 256, 0, stream>>>(kfb, qkvb, cKV, cK);
    // 4. exclusive prefix over chunks
    prefix_scan<<<dim3(BH_ * 4), 256, 0, stream>>>(cKV, cK);
    // 5. intra-chunk attention (MFMA) -> bf16 attn [B*T, C]
    intra_mfma<<<dim3(BH_ * NC_), 256, 0, stream>>>(qfb, kfb, qkvb, cKV, cK, attnb);
    // 6. out = attn @ w_out^T + b_out (fp32 out)
    gemm_bf16<0><<<dim3(EMBED / 128, M / 128), 256, 0, stream>>>(
        attnb, wob, b_out, out, nullptr, M, EMBED, EMBED);
}